// Round 1
// baseline (688.986 us; speedup 1.0000x reference)
//
#include <hip/hip_runtime.h>
#include <math.h>

// ---- constants (problem shape) ----
// B=128, N=4096, Din=128, D=128, S(slots)=8, H=256, 3 iterations.
// All heavy GEMMs use v_mfma_f32_16x16x32_bf16.
// Verified layouts (per CDNA4 guide, m89/m120):
//   C/D: col = lane&15, row = (lane>>4)*4 + reg
//   A  : A[m = lane&15][k = (lane>>4)*8 + j], j in [0,8)
//   B  : B[k = (lane>>4)*8 + j][n = lane&15]  (row-major [N][K] source => contiguous 16B/lane)

typedef __attribute__((ext_vector_type(4))) float fx4;
typedef __attribute__((ext_vector_type(8))) short sx8;
typedef __attribute__((ext_vector_type(8))) __bf16 bfx8;
typedef __attribute__((ext_vector_type(4))) unsigned short ux4;

static __device__ __forceinline__ fx4 MFMA(sx8 a, sx8 b, fx4 c) {
  return __builtin_amdgcn_mfma_f32_16x16x32_bf16(
      __builtin_bit_cast(bfx8, a), __builtin_bit_cast(bfx8, b), c, 0, 0, 0);
}

static __device__ __forceinline__ unsigned short f2bf(float f) {
  union { float f; unsigned u; } x; x.f = f;
  unsigned r = x.u + 0x7fffu + ((x.u >> 16) & 1u);  // RNE
  return (unsigned short)(r >> 16);
}
static __device__ __forceinline__ float bf2f(unsigned short u) {
  union { unsigned u; float f; } x; x.u = ((unsigned)u) << 16; return x.f;
}

// ---------------- prep: slots init + bf16 weight packing ----------------
__global__ __launch_bounds__(256) void k_prep(
    const float* __restrict__ noise, const float* __restrict__ mu,
    const float* __restrict__ lsig, const float* __restrict__ Wq,
    const float* __restrict__ Wk, const float* __restrict__ Wv,
    const float* __restrict__ Wih, const float* __restrict__ Whh,
    const float* __restrict__ W1, const float* __restrict__ W2,
    float* __restrict__ slots, unsigned short* __restrict__ wswz,
    unsigned short* __restrict__ wq_b, unsigned short* __restrict__ wih_b,
    unsigned short* __restrict__ whh_b, unsigned short* __restrict__ w1_b,
    unsigned short* __restrict__ w2_b) {
  int idx = blockIdx.x * 256 + threadIdx.x;
  if (idx < 131072) {  // slots = mu + exp(lsig)*noise
    int d = idx & 127;
    slots[idx] = mu[d] + expf(lsig[d]) * noise[idx];
    return;
  }
  idx -= 131072;
  if (idx < 32768) {  // Wkv swizzled into B-frag blocks: [(nt*4+ks)*64+lane]*8+j
    int j = idx & 7, bo = idx >> 3;
    int lane = bo & 63, ntks = bo >> 6;
    int ks = ntks & 3, nt = ntks >> 2;
    int n = nt * 16 + (lane & 15);
    int kk = ks * 32 + (lane >> 4) * 8 + j;
    float wv = (n < 128) ? Wk[n * 128 + kk] : Wv[(n - 128) * 128 + kk];
    wswz[idx] = f2bf(wv);
    return;
  }
  idx -= 32768;
  if (idx < 16384) { wq_b[idx] = f2bf(Wq[idx] * 0.08838834764831845f); return; } // fold 1/sqrt(128)
  idx -= 16384;
  if (idx < 49152) { wih_b[idx] = f2bf(Wih[idx]); return; }
  idx -= 49152;
  if (idx < 49152) { whh_b[idx] = f2bf(Whh[idx]); return; }
  idx -= 49152;
  if (idx < 32768) { w1_b[idx] = f2bf(W1[idx]); return; }
  idx -= 32768;
  w2_b[idx] = f2bf(W2[idx]);
}

// ---------------- fused LN(x) + [k|v] GEMM ----------------
// block = 256 thr (4 waves), 64 rows/block. M=64,N=256,K=128.
// wave w: LN-stages rows [w*16,w*16+16); compute: mstrip=w>>1 (32 rows), nstrip=w&1 (128 cols)
__global__ __launch_bounds__(256) void k_lnkv(
    const float* __restrict__ x, const unsigned short* __restrict__ wswz,
    unsigned short* __restrict__ kout, unsigned short* __restrict__ vout) {
  __shared__ __align__(16) short xf[4 * 4 * 64 * 8];  // [mt][ks][lane][8] bf16, 16KB
  int tid = threadIdx.x;
  int w = tid >> 6, l = tid & 63;
  int r = l & 15, seg = l >> 4;
  long rowbase = (long)blockIdx.x * 64;
  {
    const float* xp = x + (rowbase + w * 16 + r) * 128 + seg * 32;
    float v[32];
    float s = 0.f, s2 = 0.f;
#pragma unroll
    for (int i = 0; i < 8; i++) {
      fx4 t = *(const fx4*)(xp + i * 4);
      v[i * 4 + 0] = t.x; v[i * 4 + 1] = t.y; v[i * 4 + 2] = t.z; v[i * 4 + 3] = t.w;
      s += t.x + t.y + t.z + t.w;
      s2 += t.x * t.x + t.y * t.y + t.z * t.z + t.w * t.w;
    }
    s += __shfl_xor(s, 16, 64);  s += __shfl_xor(s, 32, 64);
    s2 += __shfl_xor(s2, 16, 64); s2 += __shfl_xor(s2, 32, 64);
    float mean = s * 0.0078125f;
    float var = s2 * 0.0078125f - mean * mean;
    float rstd = rsqrtf(var + 1e-5f);
#pragma unroll
    for (int q = 0; q < 4; q++) {
      sx8 t;
#pragma unroll
      for (int j = 0; j < 8; j++) t[j] = (short)f2bf((v[q * 8 + j] - mean) * rstd);
      *(sx8*)&xf[((w * 4 + seg) * 64 + (r + 16 * q)) * 8] = t;
    }
  }
  __syncthreads();
  int mstrip = w >> 1, nstrip = w & 1;
  const fx4 z4 = {0.f, 0.f, 0.f, 0.f};
  fx4 acc[2][8];
#pragma unroll
  for (int a = 0; a < 2; a++)
#pragma unroll
    for (int b = 0; b < 8; b++) acc[a][b] = z4;
#pragma unroll
  for (int ks = 0; ks < 4; ks++) {
    sx8 a0 = *(const sx8*)&xf[(((mstrip * 2 + 0) * 4 + ks) * 64 + l) * 8];
    sx8 a1 = *(const sx8*)&xf[(((mstrip * 2 + 1) * 4 + ks) * 64 + l) * 8];
#pragma unroll
    for (int nt = 0; nt < 8; nt++) {
      sx8 bfr = *(const sx8*)(wswz + (((nstrip * 8 + nt) * 4 + ks) * 64 + l) * 8);
      acc[0][nt] = MFMA(a0, bfr, acc[0][nt]);
      acc[1][nt] = MFMA(a1, bfr, acc[1][nt]);
    }
  }
  int cl = l & 15, rq = (l >> 4) * 4;
#pragma unroll
  for (int mt = 0; mt < 2; mt++) {
    long row0 = rowbase + mstrip * 32 + mt * 16 + rq;
#pragma unroll
    for (int nt = 0; nt < 8; nt++) {
      int col = nstrip * 128 + nt * 16 + cl;
      unsigned short* dst = (col < 128) ? (kout + row0 * 128 + col)
                                        : (vout + row0 * 128 + (col - 128));
#pragma unroll
      for (int rg = 0; rg < 4; rg++) dst[(long)rg * 128] = f2bf(acc[mt][nt][rg]);
    }
  }
}

// ---------------- per-iter: LN(slots) + q = slots_n @ (scale*Wq)^T ----------------
// 64 blocks x 64 thr; 16 slot-rows per block.
__global__ __launch_bounds__(64) void k_slot_pre(
    const float* __restrict__ slots, const unsigned short* __restrict__ wq_b,
    float* __restrict__ slots_n, unsigned short* __restrict__ q_b) {
  __shared__ __align__(16) short xf[4 * 64 * 8];
  int l = threadIdx.x;
  int r = l & 15, seg = l >> 4;
  long rowbase = (long)blockIdx.x * 16;
  {
    const float* xp = slots + (rowbase + r) * 128 + seg * 32;
    float* snp = slots_n + (rowbase + r) * 128 + seg * 32;
    float v[32];
    float s = 0.f, s2 = 0.f;
#pragma unroll
    for (int i = 0; i < 8; i++) {
      fx4 t = *(const fx4*)(xp + i * 4);
      v[i * 4 + 0] = t.x; v[i * 4 + 1] = t.y; v[i * 4 + 2] = t.z; v[i * 4 + 3] = t.w;
      s += t.x + t.y + t.z + t.w;
      s2 += t.x * t.x + t.y * t.y + t.z * t.z + t.w * t.w;
    }
    s += __shfl_xor(s, 16, 64);  s += __shfl_xor(s, 32, 64);
    s2 += __shfl_xor(s2, 16, 64); s2 += __shfl_xor(s2, 32, 64);
    float mean = s * 0.0078125f;
    float var = s2 * 0.0078125f - mean * mean;
    float rstd = rsqrtf(var + 1e-5f);
#pragma unroll
    for (int i = 0; i < 8; i++) {
      fx4 t = {(v[i * 4 + 0] - mean) * rstd, (v[i * 4 + 1] - mean) * rstd,
               (v[i * 4 + 2] - mean) * rstd, (v[i * 4 + 3] - mean) * rstd};
      *(fx4*)(snp + i * 4) = t;
      v[i * 4 + 0] = t.x; v[i * 4 + 1] = t.y; v[i * 4 + 2] = t.z; v[i * 4 + 3] = t.w;
    }
#pragma unroll
    for (int q = 0; q < 4; q++) {
      sx8 t;
#pragma unroll
      for (int j = 0; j < 8; j++) t[j] = (short)f2bf(v[q * 8 + j]);
      *(sx8*)&xf[(seg * 64 + (r + 16 * q)) * 8] = t;
    }
  }
  __syncthreads();
  const fx4 z4 = {0.f, 0.f, 0.f, 0.f};
  fx4 acc[8];
#pragma unroll
  for (int nt = 0; nt < 8; nt++) acc[nt] = z4;
#pragma unroll
  for (int ks = 0; ks < 4; ks++) {
    sx8 a = *(const sx8*)&xf[(ks * 64 + l) * 8];
#pragma unroll
    for (int nt = 0; nt < 8; nt++) {
      sx8 bfr = *(const sx8*)(wq_b + (nt * 16 + (l & 15)) * 128 + ks * 32 + (l >> 4) * 8);
      acc[nt] = MFMA(a, bfr, acc[nt]);
    }
  }
  int cl = l & 15, rq = (l >> 4) * 4;
#pragma unroll
  for (int nt = 0; nt < 8; nt++)
#pragma unroll
    for (int rg = 0; rg < 4; rg++)
      q_b[(rowbase + rq + rg) * 128 + nt * 16 + cl] = f2bf(acc[nt][rg]);
}

// ---------------- attention: logits->softmax->weighted V, per-chunk partials -------------
// grid = 128 batches * 4 chunks = 512 blocks, 256 thr. Chunk = 1024 rows; wave tiles of 64.
__global__ __launch_bounds__(256) void k_attn(
    const unsigned short* __restrict__ kb, const unsigned short* __restrict__ vb,
    const unsigned short* __restrict__ qb,
    float* __restrict__ upd_part, float* __restrict__ sattn_part) {
  __shared__ __align__(16) float attnbuf[4][64 * 16];  // 16KB
  __shared__ __align__(16) float updbuf[4][1024];      // 16KB
  __shared__ float sattnbuf[4][8];
  int tid = threadIdx.x, w = tid >> 6, l = tid & 63;
  int b = blockIdx.x >> 2, c = blockIdx.x & 3;
  long base = (long)b * 4096 + c * 1024;
  const unsigned short* kp = kb + base * 128;
  const unsigned short* vp = vb + base * 128;
  int s = l & 15, qd = (l >> 4) * 8;
  sx8 qf[4];
#pragma unroll
  for (int ks = 0; ks < 4; ks++) {
    if (s < 8) {
      qf[ks] = *(const sx8*)(qb + ((long)b * 8 + s) * 128 + ks * 32 + qd);
    } else {
      sx8 t;
#pragma unroll
      for (int j = 0; j < 8; j++) t[j] = 0;
      qf[ks] = t;
    }
  }
  const fx4 z4 = {0.f, 0.f, 0.f, 0.f};
  float sat_loc = 0.f;
  float ua[4][4] = {};
  int d0 = (l & 31) * 4, s0 = (l >> 5) * 4;
  for (int t = 0; t < 4; t++) {
    int tile = t * 4 + w;
    const unsigned short* kt = kp + tile * 64 * 128;
    const unsigned short* vt = vp + tile * 64 * 128;
#pragma unroll
    for (int mt = 0; mt < 4; mt++) {
      sx8 a[4];
#pragma unroll
      for (int ks = 0; ks < 4; ks++)
        a[ks] = *(const sx8*)(kt + (mt * 16 + s) * 128 + ks * 32 + qd);
      fx4 cc = z4;
#pragma unroll
      for (int ks = 0; ks < 4; ks++) cc = MFMA(a[ks], qf[ks], cc);
#pragma unroll
      for (int rg = 0; rg < 4; rg++) {
        float lg = cc[rg];
        float mx = lg;
        mx = fmaxf(mx, __shfl_xor(mx, 1, 64));
        mx = fmaxf(mx, __shfl_xor(mx, 2, 64));
        mx = fmaxf(mx, __shfl_xor(mx, 4, 64));
        float p = __expf(lg - mx);
        float sm = p;
        sm += __shfl_xor(sm, 1, 64);
        sm += __shfl_xor(sm, 2, 64);
        sm += __shfl_xor(sm, 4, 64);
        float at = p / sm + 1e-8f;
        if (s < 8) sat_loc += at;
        attnbuf[w][(mt * 16 + (l >> 4) * 4 + rg) * 16 + s] = at;
      }
    }
    // weighted V accumulation (vector ALU; v streamed coalesced from global)
#pragma unroll 2
    for (int n0 = 0; n0 < 64; n0 += 8) {
      ux4 vv[8]; fx4 at4[8];
#pragma unroll
      for (int u = 0; u < 8; u++) {
        vv[u] = *(const ux4*)(vt + (n0 + u) * 128 + d0);
        at4[u] = *(const fx4*)&attnbuf[w][(n0 + u) * 16 + s0];
      }
#pragma unroll
      for (int u = 0; u < 8; u++) {
        float v0 = bf2f(vv[u].x), v1 = bf2f(vv[u].y), v2 = bf2f(vv[u].z), v3 = bf2f(vv[u].w);
#pragma unroll
        for (int si = 0; si < 4; si++) {
          float av = at4[u][si];
          ua[si][0] += av * v0; ua[si][1] += av * v1;
          ua[si][2] += av * v2; ua[si][3] += av * v3;
        }
      }
    }
  }
#pragma unroll
  for (int si = 0; si < 4; si++) {
    fx4 tv = {ua[si][0], ua[si][1], ua[si][2], ua[si][3]};
    *(fx4*)&updbuf[w][(s0 + si) * 128 + d0] = tv;
  }
  sat_loc += __shfl_xor(sat_loc, 16, 64);
  sat_loc += __shfl_xor(sat_loc, 32, 64);
  if (l < 8) sattnbuf[w][l] = sat_loc;
  __syncthreads();
  {
    int i = tid * 4;
    fx4 o0 = *(const fx4*)&updbuf[0][i];
    fx4 o1 = *(const fx4*)&updbuf[1][i];
    fx4 o2 = *(const fx4*)&updbuf[2][i];
    fx4 o3 = *(const fx4*)&updbuf[3][i];
    fx4 o = o0 + o1 + o2 + o3;
    *(fx4*)(upd_part + ((long)b * 4 + c) * 1024 + i) = o;
    if (tid < 8)
      sattn_part[(b * 4 + c) * 8 + tid] =
          sattnbuf[0][tid] + sattnbuf[1][tid] + sattnbuf[2][tid] + sattnbuf[3][tid];
  }
}

// ---------------- GRU + MLP ----------------
// 64 blocks x 256 thr; 16 slot-rows (2 batches) per block.
__global__ __launch_bounds__(256) void k_slot_post(
    const float* __restrict__ upd_part, const float* __restrict__ sattn_part,
    const float* __restrict__ slots_n,
    const unsigned short* __restrict__ wih_b, const unsigned short* __restrict__ whh_b,
    const float* __restrict__ b_ih, const float* __restrict__ b_hh,
    const unsigned short* __restrict__ w1_b, const float* __restrict__ b1,
    const unsigned short* __restrict__ w2_b, const float* __restrict__ b2,
    float* __restrict__ out) {
  __shared__ __align__(16) short xfr[4 * 64 * 8];
  __shared__ __align__(16) short hfr[4 * 64 * 8];
  __shared__ __align__(16) short ynf[4 * 64 * 8];
  __shared__ __align__(16) short y1f[8 * 64 * 8];
  __shared__ float gx[16 * 384];
  __shared__ float gh[16 * 384];
  __shared__ float snew[16 * 132];  // padded stride vs 128 to avoid LN read conflicts
  int tid = threadIdx.x, w = tid >> 6, l = tid & 63;
  int rowbase = blockIdx.x * 16;
  int r = l & 15, seg = l >> 4;
  if (w == 0) {  // x = sum_c upd_part / sum_c sattn -> A-frags
    int row = rowbase + r;
    int bb = row >> 3, ss = row & 7;
    const float* up = upd_part + (long)bb * 4096 + ss * 128 + seg * 32;
    float a[32];
#pragma unroll
    for (int i = 0; i < 32; i++) a[i] = 0.f;
#pragma unroll
    for (int cc = 0; cc < 4; cc++)
#pragma unroll
      for (int i = 0; i < 8; i++) {
        fx4 t = *(const fx4*)(up + cc * 1024 + i * 4);
        a[i * 4 + 0] += t.x; a[i * 4 + 1] += t.y; a[i * 4 + 2] += t.z; a[i * 4 + 3] += t.w;
      }
    float sat = sattn_part[bb * 32 + ss] + sattn_part[bb * 32 + 8 + ss] +
                sattn_part[bb * 32 + 16 + ss] + sattn_part[bb * 32 + 24 + ss];
    float inv = 1.f / sat;
#pragma unroll
    for (int q = 0; q < 4; q++) {
      sx8 t;
#pragma unroll
      for (int j = 0; j < 8; j++) t[j] = (short)f2bf(a[q * 8 + j] * inv);
      *(sx8*)&xfr[(seg * 64 + (r + 16 * q)) * 8] = t;
    }
  } else if (w == 1) {  // h = slots_n -> A-frags
    const float* hp = slots_n + (long)(rowbase + r) * 128 + seg * 32;
#pragma unroll
    for (int q = 0; q < 4; q++) {
      fx4 t0 = *(const fx4*)(hp + q * 8);
      fx4 t1 = *(const fx4*)(hp + q * 8 + 4);
      sx8 t;
      t[0] = (short)f2bf(t0.x); t[1] = (short)f2bf(t0.y);
      t[2] = (short)f2bf(t0.z); t[3] = (short)f2bf(t0.w);
      t[4] = (short)f2bf(t1.x); t[5] = (short)f2bf(t1.y);
      t[6] = (short)f2bf(t1.z); t[7] = (short)f2bf(t1.w);
      *(sx8*)&hfr[(seg * 64 + (r + 16 * q)) * 8] = t;
    }
  }
  __syncthreads();
  const fx4 z4 = {0.f, 0.f, 0.f, 0.f};
  {  // GEMM1: gx = x@Wih^T, gh = h@Whh^T (N=384, wave handles 6 ntiles of each)
    fx4 ax[6], ah[6];
#pragma unroll
    for (int j = 0; j < 6; j++) { ax[j] = z4; ah[j] = z4; }
#pragma unroll
    for (int ks = 0; ks < 4; ks++) {
      sx8 a_x = *(const sx8*)&xfr[(ks * 64 + l) * 8];
      sx8 a_h = *(const sx8*)&hfr[(ks * 64 + l) * 8];
#pragma unroll
      for (int j = 0; j < 6; j++) {
        int nt = w * 6 + j;
        sx8 bx = *(const sx8*)(wih_b + (nt * 16 + (l & 15)) * 128 + ks * 32 + (l >> 4) * 8);
        sx8 bh = *(const sx8*)(whh_b + (nt * 16 + (l & 15)) * 128 + ks * 32 + (l >> 4) * 8);
        ax[j] = MFMA(a_x, bx, ax[j]);
        ah[j] = MFMA(a_h, bh, ah[j]);
      }
    }
#pragma unroll
    for (int j = 0; j < 6; j++) {
      int col = (w * 6 + j) * 16 + (l & 15);
#pragma unroll
      for (int rg = 0; rg < 4; rg++) {
        int row = (l >> 4) * 4 + rg;
        gx[row * 384 + col] = ax[j][rg];
        gh[row * 384 + col] = ah[j][rg];
      }
    }
  }
  __syncthreads();
  {  // GRU gates
    int row = tid >> 4, j0 = (tid & 15) * 8;
#pragma unroll
    for (int j = j0; j < j0 + 8; j++) {
      float xr = gx[row * 384 + j] + b_ih[j];
      float xz = gx[row * 384 + 128 + j] + b_ih[128 + j];
      float xn = gx[row * 384 + 256 + j] + b_ih[256 + j];
      float hr = gh[row * 384 + j] + b_hh[j];
      float hz = gh[row * 384 + 128 + j] + b_hh[128 + j];
      float hn = gh[row * 384 + 256 + j] + b_hh[256 + j];
      float rr = 1.f / (1.f + __expf(-(xr + hr)));
      float zz = 1.f / (1.f + __expf(-(xz + hz)));
      float nn = tanhf(xn + rr * hn);
      float h = slots_n[(long)(rowbase + row) * 128 + j];
      snew[row * 132 + j] = (1.f - zz) * nn + zz * h;
    }
  }
  __syncthreads();
  if (w == 0) {  // LN(snew) -> A-frags
    float v[32];
    float s = 0.f, s2 = 0.f;
#pragma unroll
    for (int i = 0; i < 32; i++) {
      float t = snew[r * 132 + seg * 32 + i];
      v[i] = t; s += t; s2 += t * t;
    }
    s += __shfl_xor(s, 16, 64);  s += __shfl_xor(s, 32, 64);
    s2 += __shfl_xor(s2, 16, 64); s2 += __shfl_xor(s2, 32, 64);
    float mean = s * 0.0078125f;
    float var = s2 * 0.0078125f - mean * mean;
    float rstd = rsqrtf(var + 1e-5f);
#pragma unroll
    for (int q = 0; q < 4; q++) {
      sx8 t;
#pragma unroll
      for (int j = 0; j < 8; j++) t[j] = (short)f2bf((v[q * 8 + j] - mean) * rstd);
      *(sx8*)&ynf[(seg * 64 + (r + 16 * q)) * 8] = t;
    }
  }
  __syncthreads();
  {  // GEMM2: y1 = relu(LN@W1^T + b1), scatter into A-frag layout for GEMM3
    fx4 y[4];
#pragma unroll
    for (int j = 0; j < 4; j++) y[j] = z4;
#pragma unroll
    for (int ks = 0; ks < 4; ks++) {
      sx8 a = *(const sx8*)&ynf[(ks * 64 + l) * 8];
#pragma unroll
      for (int j = 0; j < 4; j++) {
        int nt = w * 4 + j;
        sx8 bf = *(const sx8*)(w1_b + (nt * 16 + (l & 15)) * 128 + ks * 32 + (l >> 4) * 8);
        y[j] = MFMA(a, bf, y[j]);
      }
    }
#pragma unroll
    for (int j = 0; j < 4; j++) {
      int col = (w * 4 + j) * 16 + (l & 15);
      float bias = b1[col];
      int ks3 = col >> 5, qq = (col >> 3) & 3, jj = col & 7;
#pragma unroll
      for (int rg = 0; rg < 4; rg++) {
        float val = fmaxf(y[j][rg] + bias, 0.f);
        int m = (l >> 4) * 4 + rg;
        y1f[(ks3 * 64 + m + 16 * qq) * 8 + jj] = (short)f2bf(val);
      }
    }
  }
  __syncthreads();
  {  // GEMM3: out = snew + y1@W2^T + b2
    fx4 zz2[2];
    zz2[0] = z4; zz2[1] = z4;
#pragma unroll
    for (int ks = 0; ks < 8; ks++) {
      sx8 a = *(const sx8*)&y1f[(ks * 64 + l) * 8];
#pragma unroll
      for (int j = 0; j < 2; j++) {
        sx8 bf = *(const sx8*)(w2_b + ((w * 2 + j) * 16 + (l & 15)) * 256 + ks * 32 + (l >> 4) * 8);
        zz2[j] = MFMA(a, bf, zz2[j]);
      }
    }
#pragma unroll
    for (int j = 0; j < 2; j++) {
      int col = (w * 2 + j) * 16 + (l & 15);
      float bias = b2[col];
#pragma unroll
      for (int rg = 0; rg < 4; rg++) {
        int row = (l >> 4) * 4 + rg;
        out[(long)(rowbase + row) * 128 + col] = snew[row * 132 + col] + zz2[j][rg] + bias;
      }
    }
  }
}

extern "C" void kernel_launch(void* const* d_in, const int* in_sizes, int n_in,
                              void* d_out, int out_size, void* d_ws, size_t ws_size,
                              hipStream_t stream) {
  (void)in_sizes; (void)n_in; (void)out_size; (void)ws_size;
  const float* x = (const float*)d_in[0];
  const float* noise = (const float*)d_in[1];
  const float* mu = (const float*)d_in[2];
  const float* lsig = (const float*)d_in[3];
  const float* Wq = (const float*)d_in[4];
  const float* Wk = (const float*)d_in[5];
  const float* Wv = (const float*)d_in[6];
  const float* Wih = (const float*)d_in[7];
  const float* Whh = (const float*)d_in[8];
  const float* b_ih = (const float*)d_in[9];
  const float* b_hh = (const float*)d_in[10];
  const float* W1 = (const float*)d_in[11];
  const float* b1 = (const float*)d_in[12];
  const float* W2 = (const float*)d_in[13];
  const float* b2 = (const float*)d_in[14];

  char* ws = (char*)d_ws;
  size_t off = 0;
  auto take = [&](size_t bytes) {
    char* p = ws + off;
    off += (bytes + 255) & ~(size_t)255;
    return p;
  };
  unsigned short* kb = (unsigned short*)take(134217728);      // k bf16 (B,N,128)
  unsigned short* vb = (unsigned short*)take(134217728);      // v bf16
  unsigned short* wswz = (unsigned short*)take(65536);
  unsigned short* wq_b = (unsigned short*)take(32768);
  unsigned short* wih_b = (unsigned short*)take(98304);
  unsigned short* whh_b = (unsigned short*)take(98304);
  unsigned short* w1_b = (unsigned short*)take(65536);
  unsigned short* w2_b = (unsigned short*)take(65536);
  float* slots = (float*)take(524288);
  float* slots_n = (float*)take(524288);
  unsigned short* q_b = (unsigned short*)take(262144);
  float* upd_part = (float*)take(2097152);    // (B,4,8,128)
  float* sattn_part = (float*)take(16384);    // (B,4,8)

  k_prep<<<1344, 256, 0, stream>>>(noise, mu, lsig, Wq, Wk, Wv, Wih, Whh, W1, W2,
                                   slots, wswz, wq_b, wih_b, whh_b, w1_b, w2_b);
  k_lnkv<<<8192, 256, 0, stream>>>(x, wswz, kb, vb);
  for (int it = 0; it < 3; it++) {
    k_slot_pre<<<64, 64, 0, stream>>>(slots, wq_b, slots_n, q_b);
    k_attn<<<512, 256, 0, stream>>>(kb, vb, q_b, upd_part, sattn_part);
    float* outp = (it == 2) ? (float*)d_out : slots;
    k_slot_post<<<64, 256, 0, stream>>>(upd_part, sattn_part, slots_n, wih_b, whh_b,
                                        b_ih, b_hh, w1_b, b1, w2_b, b2, outp);
  }
}